// Round 8
// baseline (1974.022 us; speedup 1.0000x reference)
//
#include <hip/hip_runtime.h>

// Seq2SeqDecoder: 2-layer GRU (reset_after) + logit projection, MI355X/gfx950.
// B=32 T=64 V=32000 E=512 H=1024.
//   phase 0: transpose-convert weights to bf16 [N][K]; build xin bf16; init states
//   phase 1: MX0 = xin @ k0t + b0[0]                  (bf16 MFMA GEMM, 19.3 GF)
//   phase 2: ONE cooperative persistent kernel runs the whole recurrence.
//     R3: rel/acq barrier 22.6 us/step; R4 tree 19.2; R5 fence-free+sc1 16.3;
//     R6 FAILED (300 VGPR -> coop launch rejected); R7 burst h-loads: 16.6
//     (atomic-serialization theory falsified).
//     R8: MEASUREMENT ROUND. Compute pass duplicated with opaque-offset loads
//     (asm-sunk, no writes) -> dur delta / 66 = compute time C; barrier B =
//     16.6 - C. Pre-committed: B>=13 -> R9 minimal-hop flag sync; C>=9 ->
//     attack weight path.
//   phase 3: logits = seq1 @ Wdt + bd   (grid swapped dim3(16,250): row-tiles
//     innermost so each 262KB Wdt strip is read once, not streamed 16x ->
//     FETCH 619MB should drop to ~100-200MB)
//   phase 4: final states -> d_out tail

typedef __attribute__((ext_vector_type(8))) short bf16x8;
typedef __attribute__((ext_vector_type(4))) float f32x4;
typedef __attribute__((ext_vector_type(2))) unsigned long long u64x2;
typedef unsigned short u16;
typedef unsigned int u32;

#define CHAIN_BLOCKS 192
#define BAR_GROUPS 16
#define BAR_GROUP_SZ 12          // CHAIN_BLOCKS / BAR_GROUPS
#define BAR_WORDS (33 * 64)      // 16 leaf + 1 root + 16 go lines, 256B apart

__device__ __forceinline__ u16 f2bf(float f) {
  unsigned int x = __float_as_uint(f);
  x += 0x7fffu + ((x >> 16) & 1u);   // RNE
  return (u16)(x >> 16);
}

// ---- agent-scope (sc1) access helpers: L3 is the coherence point ----------
__device__ __forceinline__ bf16x8 aload16(const u16* p) {
  unsigned long long lo = __hip_atomic_load((const unsigned long long*)p,
      __ATOMIC_RELAXED, __HIP_MEMORY_SCOPE_AGENT);
  unsigned long long hi = __hip_atomic_load((const unsigned long long*)(p + 4),
      __ATOMIC_RELAXED, __HIP_MEMORY_SCOPE_AGENT);
  union { u64x2 u; bf16x8 v; } t;
  t.u.x = lo; t.u.y = hi;
  return t.v;
}
__device__ __forceinline__ float aloadf(const float* p) {
  return __uint_as_float(__hip_atomic_load((const u32*)p, __ATOMIC_RELAXED,
                                           __HIP_MEMORY_SCOPE_AGENT));
}
__device__ __forceinline__ void astoref(float* p, float v) {
  __hip_atomic_store((u32*)p, __float_as_uint(v), __ATOMIC_RELAXED,
                     __HIP_MEMORY_SCOPE_AGENT);
}
__device__ __forceinline__ void astore32(u16* p, u32 v) {
  __hip_atomic_store((u32*)p, v, __ATOMIC_RELAXED, __HIP_MEMORY_SCOPE_AGENT);
}

// Fence-free grid barrier (monotonic counters, reset by k_init each launch).
__device__ __forceinline__ void gridbar(u32* bar, u32 phase) {
  asm volatile("s_waitcnt vmcnt(0)" ::: "memory");
  __syncthreads();
  if (threadIdx.x == 0) {
    const int g = blockIdx.x & (BAR_GROUPS - 1);
    u32* leaf = bar + g * 64;
    u32* root = bar + BAR_GROUPS * 64;
    u32* go   = bar + (BAR_GROUPS + 1 + g) * 64;
    u32 prev = __hip_atomic_fetch_add(leaf, 1u, __ATOMIC_RELAXED,
                                      __HIP_MEMORY_SCOPE_AGENT);
    if ((prev + 1u) % BAR_GROUP_SZ == 0u) {
      __hip_atomic_fetch_add(root, 1u, __ATOMIC_RELAXED,
                             __HIP_MEMORY_SCOPE_AGENT);
      while (__hip_atomic_load(root, __ATOMIC_RELAXED,
                               __HIP_MEMORY_SCOPE_AGENT) < BAR_GROUPS * phase)
        __builtin_amdgcn_s_sleep(1);
      __hip_atomic_store(go, phase, __ATOMIC_RELAXED,
                         __HIP_MEMORY_SCOPE_AGENT);
    } else {
      while (__hip_atomic_load(go, __ATOMIC_RELAXED,
                               __HIP_MEMORY_SCOPE_AGENT) < phase)
        __builtin_amdgcn_s_sleep(1);
    }
  }
  __syncthreads();
}

// ---- transpose + convert: in f32 [R][C] -> out bf16 [C][R] ----------------
__global__ void k_tconv(const float* __restrict__ in, u16* __restrict__ out,
                        int R, int C) {
  __shared__ float t[32][33];
  int tx = threadIdx.x, ty = threadIdx.y;          // 32 x 8
  int c0 = blockIdx.x * 32, r0 = blockIdx.y * 32;
#pragma unroll
  for (int i = 0; i < 4; ++i)
    t[ty + i * 8][tx] = in[(long)(r0 + ty + i * 8) * C + c0 + tx];
  __syncthreads();
#pragma unroll
  for (int i = 0; i < 4; ++i)
    out[(long)(c0 + ty + i * 8) * R + r0 + tx] = f2bf(t[tx][ty + i * 8]);
}

// ---- xin[bt][0:512]=emb[X[bt]], [512:1536]=state[1][b]  (bf16) ------------
__global__ void k_embed(const int* __restrict__ X, const float* __restrict__ state,
                        const float* __restrict__ emb, u16* __restrict__ xin) {
  int bt = blockIdx.x;
  int b = bt >> 6;
  int tok = X[bt];
  const float* er = emb + (long)tok * 512;
  const float* cr = state + 32 * 1024 + b * 1024;  // state[-1] == state[1]
  for (int c = threadIdx.x; c < 1536; c += 256) {
    float v = (c < 512) ? er[c] : cr[c - 512];
    xin[(long)bt * 1536 + c] = f2bf(v);
  }
}

// ---- init: H0 slot0 = bf16(state[0]); parity-1 slots hold h(-1) -----------
__global__ void k_init(const float* __restrict__ state, u16* __restrict__ H0,
                       u16* __restrict__ H1, float* __restrict__ h0f,
                       float* __restrict__ h1f, u32* __restrict__ bar) {
  int i = blockIdx.x * 256 + threadIdx.x;          // grid 128 -> 32768
  if (i < BAR_WORDS) bar[i] = 0u;                  // barrier counters reset
  float v0 = state[i], v1 = state[32768 + i];
  H0[i] = f2bf(v0);             // H0 slot 0  (holds h0(-1))
  h0f[32768 + i] = v0;          // parity 1
  H1[32768 + i] = f2bf(v1);     // parity 1   (holds h1(-1))
  h1f[32768 + i] = v1;
}

// ---- bf16 GEMM: C[M,N]f32 = A[M,K] @ Bt[N,K]^T + bias[N] ------------------
// 128x128 tile, BK=32, 256 thr = 4 waves. R8: r0 from blockIdx.x (gridDim.x =
// M/128, dispatched fastest) so same-column-strip tiles run together -> the
// B-panel strip is read once from HBM instead of M/128 times.
__global__ void k_gemm(const u16* __restrict__ A, const u16* __restrict__ Bt,
                       const float* __restrict__ bias, float* __restrict__ C,
                       int M, int N, int K) {
  __shared__ u16 As[128][40];
  __shared__ u16 Bs[128][40];
  int tid = threadIdx.x;
  int w = tid >> 6, l = tid & 63;
  int ln = l & 15, lk = l >> 4;
  int r0 = blockIdx.x * 128, c0 = blockIdx.y * 128;
  int qr = (w & 1) * 64, qc = (w >> 1) * 64;
  int sr = tid >> 1, sc = (tid & 1) * 16;
  const u16* Ap = A + (long)(r0 + sr) * K + sc;
  const u16* Bp = Bt + (long)(c0 + sr) * K + sc;
  f32x4 acc[4][4] = {};
  for (int kt = 0; kt < K; kt += 32) {
    bf16x8 a0 = *(const bf16x8*)(Ap + kt);
    bf16x8 a1 = *(const bf16x8*)(Ap + kt + 8);
    bf16x8 b0 = *(const bf16x8*)(Bp + kt);
    bf16x8 b1 = *(const bf16x8*)(Bp + kt + 8);
    __syncthreads();
    *(bf16x8*)(&As[sr][sc]) = a0;  *(bf16x8*)(&As[sr][sc + 8]) = a1;
    *(bf16x8*)(&Bs[sr][sc]) = b0;  *(bf16x8*)(&Bs[sr][sc + 8]) = b1;
    __syncthreads();
    bf16x8 af[4], bfv[4];
#pragma unroll
    for (int mt = 0; mt < 4; ++mt)
      af[mt] = *(const bf16x8*)(&As[qr + mt * 16 + ln][lk * 8]);
#pragma unroll
    for (int nt = 0; nt < 4; ++nt)
      bfv[nt] = *(const bf16x8*)(&Bs[qc + nt * 16 + ln][lk * 8]);
#pragma unroll
    for (int mt = 0; mt < 4; ++mt)
#pragma unroll
      for (int nt = 0; nt < 4; ++nt)
        acc[mt][nt] = __builtin_amdgcn_mfma_f32_16x16x32_bf16(
            af[mt], bfv[nt], acc[mt][nt], 0, 0, 0);
  }
#pragma unroll
  for (int mt = 0; mt < 4; ++mt)
#pragma unroll
    for (int nt = 0; nt < 4; ++nt)
#pragma unroll
      for (int r = 0; r < 4; ++r) {
        int row = r0 + qr + mt * 16 + lk * 4 + r;
        int col = c0 + qc + nt * 16 + ln;
        C[(long)row * N + col] = acc[mt][nt][r] + bias[col];
      }
}

// ---- persistent cooperative recurrence kernel -----------------------------
// R8 probe: compute pass duplicated (opaque-offset loads, asm-sunk results,
// sched_barrier-fenced). dur delta vs R7 / 66 = compute time per step.
__global__ void __launch_bounds__(256, 1)
k_chain(const u16* __restrict__ rk0t, const u16* __restrict__ k1t,
        const u16* __restrict__ rk1t, const float* __restrict__ MX0,
        const float* __restrict__ b0, const float* __restrict__ b1,
        float* __restrict__ MX1, u16* __restrict__ H0, u16* __restrict__ H1,
        float* __restrict__ h0f, float* __restrict__ h1f,
        u16* __restrict__ seq1, u32* __restrict__ bar) {
  __shared__ float red[2][3][4][64];
  __shared__ u16 hbS[32][16];
  const int blk = blockIdx.x;
  const int type = blk >> 6;          // 0:L0  1:MX1  2:L1
  const int cb = blk & 63;
  const int j0 = cb << 4;             // 16 h-cols per block
  const int tid = threadIdx.x;
  const int w = tid >> 6, l = tid & 63;
  const int ln = l & 15, lk = l >> 4;
  const int rt = w & 1, kh = w >> 1;  // row-tile (16 rows), K-half (512)

  const u16* Wt = (type == 0) ? rk0t : (type == 1) ? k1t : rk1t;
  const u16* wp = Wt + (long)(j0 + ln) * 1024 + kh * 512 + lk * 8;

  for (int s = 0; s < 66; ++s) {
    const int tt = (type == 0) ? s : (type == 1) ? s - 1 : s - 2;
    const bool active = (tt >= 0) && (tt < 64);
    f32x4 acc[3] = {};
    if (active) {
      const u16* Ab =
          (type == 0) ? H0 + (long)(tt & 3) * 32768 :          // h0(t-1)
          (type == 1) ? H0 + (long)((tt + 1) & 3) * 32768 :    // h0(t)
                        H1 + (long)((tt + 1) & 1) * 32768;     // h1(t-1)
      const u16* hp = Ab + (rt * 16 + ln) * 1024 + kh * 512 + lk * 8;
      // pass 1 (real): burst h loads, then MFMA with L2 weight loads
      bf16x8 afr[16];
#pragma unroll
      for (int ks = 0; ks < 16; ++ks) afr[ks] = aload16(hp + ks * 32);
#pragma unroll
      for (int ks = 0; ks < 16; ++ks) {
        bf16x8 bv0 = *(const bf16x8*)(wp + ks * 32);
        bf16x8 bv1 = *(const bf16x8*)(wp + (1L << 20) + ks * 32);
        bf16x8 bv2 = *(const bf16x8*)(wp + (2L << 20) + ks * 32);
        acc[0] = __builtin_amdgcn_mfma_f32_16x16x32_bf16(afr[ks], bv0, acc[0], 0, 0, 0);
        acc[1] = __builtin_amdgcn_mfma_f32_16x16x32_bf16(afr[ks], bv1, acc[1], 0, 0, 0);
        acc[2] = __builtin_amdgcn_mfma_f32_16x16x32_bf16(afr[ks], bv2, acc[2], 0, 0, 0);
      }
      // ---- R8 PROBE: duplicate pass, opaque zero offset defeats CSE -------
      __builtin_amdgcn_sched_barrier(0);
      {
        u32 zoff;
        asm volatile("v_mov_b32 %0, 0" : "=v"(zoff));
        const u16* hp2 = hp + zoff;
        const u16* wp2 = wp + zoff;
        bf16x8 afr2[16];
#pragma unroll
        for (int ks = 0; ks < 16; ++ks) afr2[ks] = aload16(hp2 + ks * 32);
        f32x4 accP[3] = {};
#pragma unroll
        for (int ks = 0; ks < 16; ++ks) {
          bf16x8 p0 = *(const bf16x8*)(wp2 + ks * 32);
          bf16x8 p1 = *(const bf16x8*)(wp2 + (1L << 20) + ks * 32);
          bf16x8 p2 = *(const bf16x8*)(wp2 + (2L << 20) + ks * 32);
          accP[0] = __builtin_amdgcn_mfma_f32_16x16x32_bf16(afr2[ks], p0, accP[0], 0, 0, 0);
          accP[1] = __builtin_amdgcn_mfma_f32_16x16x32_bf16(afr2[ks], p1, accP[1], 0, 0, 0);
          accP[2] = __builtin_amdgcn_mfma_f32_16x16x32_bf16(afr2[ks], p2, accP[2], 0, 0, 0);
        }
#pragma unroll
        for (int g = 0; g < 3; ++g)
#pragma unroll
          for (int r = 0; r < 4; ++r)
            asm volatile("" :: "v"(accP[g][r]));   // keep live (rule #17)
      }
      __builtin_amdgcn_sched_barrier(0);
      // ---------------------------------------------------------------------
      if (kh == 1) {
#pragma unroll
        for (int g = 0; g < 3; ++g)
#pragma unroll
          for (int r = 0; r < 4; ++r)
            red[rt][g][r][l] = acc[g][r];
      }
    }
    __syncthreads();
    if (active && kh == 0) {
#pragma unroll
      for (int r = 0; r < 4; ++r) {
        const int row = rt * 16 + lk * 4 + r;    // batch b
        const int j = j0 + ln;
        float mz = acc[0][r] + red[rt][0][r][l];
        float mr = acc[1][r] + red[rt][1][r][l];
        float mh = acc[2][r] + red[rt][2][r][l];
        if (type == 1) {
          float* o = MX1 + (long)(tt & 1) * 98304 + (long)row * 3072;
          astoref(o + j,        mz + b1[j]);
          astoref(o + 1024 + j, mr + b1[1024 + j]);
          astoref(o + 2048 + j, mh + b1[2048 + j]);
        } else {
          const float* bias = (type == 0) ? b0 + 3072 : b1 + 3072;  // b[1]
          float mxz, mxr, mxh;
          if (type == 0) {
            const float* mx = MX0 + ((long)row * 64 + tt) * 3072;
            mxz = mx[j]; mxr = mx[1024 + j]; mxh = mx[2048 + j];
          } else {
            const float* mx = MX1 + (long)(tt & 1) * 98304 + (long)row * 3072;
            mxz = aloadf(mx + j);
            mxr = aloadf(mx + 1024 + j);
            mxh = aloadf(mx + 2048 + j);
          }
          float miz = mz + bias[j];
          float mir = mr + bias[1024 + j];
          float mih = mh + bias[2048 + j];
          float z  = 1.f / (1.f + expf(-(mxz + miz)));
          float rg = 1.f / (1.f + expf(-(mxr + mir)));
          float hh = tanhf(mxh + rg * mih);
          float* hf = (type == 0) ? h0f : h1f;
          float hold = hf[(long)((tt + 1) & 1) * 32768 + row * 1024 + j];
          float hn = z * hold + (1.f - z) * hh;
          hf[(long)(tt & 1) * 32768 + row * 1024 + j] = hn;    // private
          hbS[row][ln] = f2bf(hn);                             // stage bf16
        }
      }
    }
    if (type != 1) {
      __syncthreads();
      if (active) {
        // cooperative u32 writeout of the staged 32x16 bf16 tile
        const int row = tid >> 3, cp = tid & 7;
        const u32 v = ((const u32*)&hbS[row][0])[cp];
        const int j = j0 + cp * 2;
        if (type == 0) {
          astore32(&H0[(long)((tt + 1) & 3) * 32768 + row * 1024 + j], v);
        } else {
          astore32(&H1[(long)(tt & 1) * 32768 + row * 1024 + j], v);
          *(u32*)&seq1[((long)row * 64 + tt) * 1024 + j] = v;  // normal store
        }
      }
    }
    gridbar(bar, (u32)(s + 1));
  }
}

__global__ void k_states(const float* __restrict__ h0, const float* __restrict__ h1,
                         float* __restrict__ out) {
  int i = blockIdx.x * 256 + threadIdx.x;        // grid 128
  out[i] = h0[i];
  out[32768 + i] = h1[i];
}

extern "C" void kernel_launch(void* const* d_in, const int* in_sizes, int n_in,
                              void* d_out, int out_size, void* d_ws, size_t ws_size,
                              hipStream_t stream) {
  const int*   X     = (const int*)  d_in[0];
  const float* state = (const float*)d_in[1];
  const float* emb   = (const float*)d_in[2];
  const float* k0    = (const float*)d_in[3];
  const float* rk0   = (const float*)d_in[4];
  const float* b0    = (const float*)d_in[5];
  const float* k1    = (const float*)d_in[6];
  const float* rk1   = (const float*)d_in[7];
  const float* b1    = (const float*)d_in[8];
  const float* Wd    = (const float*)d_in[9];
  const float* bd    = (const float*)d_in[10];
  float* out = (float*)d_out;

  char* p = (char*)d_ws;
  size_t off = 0;
  auto alloc = [&](size_t bytes) {
    char* r = p + off;
    off += (bytes + 255) & ~(size_t)255;
    return r;
  };
  u16* k0t  = (u16*)alloc(3072UL * 1536 * 2);
  u16* rk0t = (u16*)alloc(3072UL * 1024 * 2);
  u16* k1t  = (u16*)alloc(3072UL * 1024 * 2);
  u16* rk1t = (u16*)alloc(3072UL * 1024 * 2);
  u16* Wdt  = (u16*)alloc(32000UL * 1024 * 2);
  u16* xin  = (u16*)alloc(2048UL * 1536 * 2);
  float* MX0 = (float*)alloc(2048UL * 3072 * 4);
  float* MX1 = (float*)alloc(2UL * 32 * 3072 * 4);
  u16* H0   = (u16*)alloc(4UL * 32768 * 2);      // 4-slot rotation
  u16* H1   = (u16*)alloc(2UL * 32768 * 2);
  float* h0f = (float*)alloc(2UL * 32768 * 4);
  float* h1f = (float*)alloc(2UL * 32768 * 4);
  u16* seq1 = (u16*)alloc(2048UL * 1024 * 2);
  u32* bar  = (u32*)alloc(BAR_WORDS * 4);
  if (off > ws_size) return;   // ws too small -> poison output signature

  dim3 tb(32, 8);
  k_tconv<<<dim3(3072 / 32, 1536 / 32), tb, 0, stream>>>(k0, k0t, 1536, 3072);
  k_tconv<<<dim3(3072 / 32, 1024 / 32), tb, 0, stream>>>(rk0, rk0t, 1024, 3072);
  k_tconv<<<dim3(3072 / 32, 1024 / 32), tb, 0, stream>>>(k1, k1t, 1024, 3072);
  k_tconv<<<dim3(3072 / 32, 1024 / 32), tb, 0, stream>>>(rk1, rk1t, 1024, 3072);
  k_tconv<<<dim3(32000 / 32, 1024 / 32), tb, 0, stream>>>(Wd, Wdt, 1024, 32000);
  k_embed<<<2048, 256, 0, stream>>>(X, state, emb, xin);
  k_init<<<128, 256, 0, stream>>>(state, H0, H1, h0f, h1f, bar);

  // phase 1: MX0 = xin @ k0t + b0[0]   (grid: rows x cols = 16 x 24)
  k_gemm<<<dim3(16, 24), 256, 0, stream>>>(xin, k0t, b0, MX0, 2048, 3072, 1536);

  // phase 2: full recurrence in one cooperative kernel (fence-free barrier)
  {
    void* args[] = {(void*)&rk0t, (void*)&k1t, (void*)&rk1t, (void*)&MX0,
                    (void*)&b0,   (void*)&b1,  (void*)&MX1,  (void*)&H0,
                    (void*)&H1,   (void*)&h0f, (void*)&h1f,  (void*)&seq1,
                    (void*)&bar};
    hipLaunchCooperativeKernel((void*)k_chain, dim3(CHAIN_BLOCKS), dim3(256),
                               args, 0, stream);
  }

  // phase 3: logits = seq1 @ Wdt + bd  (grid: rows x cols = 16 x 250 -> each
  // Wdt strip read once; row-tiles of a strip are dispatch-adjacent)
  k_gemm<<<dim3(16, 250), 256, 0, stream>>>(seq1, Wdt, bd, out,
                                            2048, 32000, 1024);
  // phase 4: final states (t=63 -> parity 1)
  k_states<<<128, 256, 0, stream>>>(h0f + 32768, h1f + 32768, out + 65536000UL);
}

// Round 9
// 1358.021 us; speedup vs baseline: 1.4536x; 1.4536x over previous
//
#include <hip/hip_runtime.h>

// Seq2SeqDecoder: 2-layer GRU (reset_after) + logit projection, MI355X/gfx950.
// B=32 T=64 V=32000 E=512 H=1024.
//   phase 0: transpose-convert weights to bf16 [N][K]; build xin bf16; init states
//   phase 1: MX0 = xin @ k0t + b0[0]                  (bf16 MFMA GEMM, 19.3 GF)
//   phase 2: ONE cooperative persistent kernel runs the whole recurrence.
//     R3 22.6us/step; R4 tree 19.2; R5 fence-free sc1 16.3; R7 burst 16.6.
//     R8 MEASURED: compute pass C=8.2us/step, barrier B=8.4us/step.
//     R9: (a) per-timestep buffers (H0/H1 65 slots, MX1 64 slots) -> every
//         cross-block address written ONCE -> consumers use NORMAL CACHED
//         loads (L2-shared within XCD; L3 traffic 12MB -> 0.5MB/step).
//         One agent-ACQUIRE (buffer_inv) at kernel entry; producers still
//         sc1 write-through + vmcnt drain before arrival.
//         (b) WAR-free => grid barrier DECOUPLED into per-type counters:
//         L0 polls cnt0 (own group), MX1 polls cnt0, L1 polls cnt1&cnt2.
//         Types pipeline-overlap; critical path = L0 loop only.
//   phase 3: logits = seq1 @ Wdt + bd                 (134.2 GF) -> d_out
//   phase 4: final states -> d_out tail

typedef __attribute__((ext_vector_type(8))) short bf16x8;
typedef __attribute__((ext_vector_type(4))) float f32x4;
typedef unsigned short u16;
typedef unsigned int u32;

#define CHAIN_BLOCKS 192
#define BAR_WORDS (8 * 64)       // cnt0/cnt1/cnt2 on separate 256B lines

__device__ __forceinline__ u16 f2bf(float f) {
  unsigned int x = __float_as_uint(f);
  x += 0x7fffu + ((x >> 16) & 1u);   // RNE
  return (u16)(x >> 16);
}

// sc1 write-through stores (visible at L3 after vmcnt drain)
__device__ __forceinline__ void astoref(float* p, float v) {
  __hip_atomic_store((u32*)p, __float_as_uint(v), __ATOMIC_RELAXED,
                     __HIP_MEMORY_SCOPE_AGENT);
}
__device__ __forceinline__ void astore32(u16* p, u32 v) {
  __hip_atomic_store((u32*)p, v, __ATOMIC_RELAXED, __HIP_MEMORY_SCOPE_AGENT);
}

// ---- transpose + convert: in f32 [R][C] -> out bf16 [C][R] ----------------
__global__ void k_tconv(const float* __restrict__ in, u16* __restrict__ out,
                        int R, int C) {
  __shared__ float t[32][33];
  int tx = threadIdx.x, ty = threadIdx.y;          // 32 x 8
  int c0 = blockIdx.x * 32, r0 = blockIdx.y * 32;
#pragma unroll
  for (int i = 0; i < 4; ++i)
    t[ty + i * 8][tx] = in[(long)(r0 + ty + i * 8) * C + c0 + tx];
  __syncthreads();
#pragma unroll
  for (int i = 0; i < 4; ++i)
    out[(long)(c0 + ty + i * 8) * R + r0 + tx] = f2bf(t[tx][ty + i * 8]);
}

// ---- xin[bt][0:512]=emb[X[bt]], [512:1536]=state[1][b]  (bf16) ------------
__global__ void k_embed(const int* __restrict__ X, const float* __restrict__ state,
                        const float* __restrict__ emb, u16* __restrict__ xin) {
  int bt = blockIdx.x;
  int b = bt >> 6;
  int tok = X[bt];
  const float* er = emb + (long)tok * 512;
  const float* cr = state + 32 * 1024 + b * 1024;  // state[-1] == state[1]
  for (int c = threadIdx.x; c < 1536; c += 256) {
    float v = (c < 512) ? er[c] : cr[c - 512];
    xin[(long)bt * 1536 + c] = f2bf(v);
  }
}

// ---- init: H0/H1 slot0 = bf16(state); h0f/h1f parity1 = state -------------
__global__ void k_init(const float* __restrict__ state, u16* __restrict__ H0,
                       u16* __restrict__ H1, float* __restrict__ h0f,
                       float* __restrict__ h1f, u32* __restrict__ bar) {
  int i = blockIdx.x * 256 + threadIdx.x;          // grid 128 -> 32768
  if (i < BAR_WORDS) bar[i] = 0u;                  // counters reset
  float v0 = state[i], v1 = state[32768 + i];
  H0[i] = f2bf(v0);             // slot 0 = h0(-1)
  h0f[32768 + i] = v0;          // parity 1
  H1[i] = f2bf(v1);             // slot 0 = h1(-1)
  h1f[32768 + i] = v1;
}

// ---- bf16 GEMM: C[M,N]f32 = A[M,K] @ Bt[N,K]^T + bias[N] ------------------
// 128x128 tile, BK=32, 256 thr = 4 waves. r0 from blockIdx.x (fastest) so
// same-column-strip tiles are dispatch-adjacent (B-strip read once).
__global__ void k_gemm(const u16* __restrict__ A, const u16* __restrict__ Bt,
                       const float* __restrict__ bias, float* __restrict__ C,
                       int M, int N, int K) {
  __shared__ u16 As[128][40];
  __shared__ u16 Bs[128][40];
  int tid = threadIdx.x;
  int w = tid >> 6, l = tid & 63;
  int ln = l & 15, lk = l >> 4;
  int r0 = blockIdx.x * 128, c0 = blockIdx.y * 128;
  int qr = (w & 1) * 64, qc = (w >> 1) * 64;
  int sr = tid >> 1, sc = (tid & 1) * 16;
  const u16* Ap = A + (long)(r0 + sr) * K + sc;
  const u16* Bp = Bt + (long)(c0 + sr) * K + sc;
  f32x4 acc[4][4] = {};
  for (int kt = 0; kt < K; kt += 32) {
    bf16x8 a0 = *(const bf16x8*)(Ap + kt);
    bf16x8 a1 = *(const bf16x8*)(Ap + kt + 8);
    bf16x8 b0 = *(const bf16x8*)(Bp + kt);
    bf16x8 b1 = *(const bf16x8*)(Bp + kt + 8);
    __syncthreads();
    *(bf16x8*)(&As[sr][sc]) = a0;  *(bf16x8*)(&As[sr][sc + 8]) = a1;
    *(bf16x8*)(&Bs[sr][sc]) = b0;  *(bf16x8*)(&Bs[sr][sc + 8]) = b1;
    __syncthreads();
    bf16x8 af[4], bfv[4];
#pragma unroll
    for (int mt = 0; mt < 4; ++mt)
      af[mt] = *(const bf16x8*)(&As[qr + mt * 16 + ln][lk * 8]);
#pragma unroll
    for (int nt = 0; nt < 4; ++nt)
      bfv[nt] = *(const bf16x8*)(&Bs[qc + nt * 16 + ln][lk * 8]);
#pragma unroll
    for (int mt = 0; mt < 4; ++mt)
#pragma unroll
      for (int nt = 0; nt < 4; ++nt)
        acc[mt][nt] = __builtin_amdgcn_mfma_f32_16x16x32_bf16(
            af[mt], bfv[nt], acc[mt][nt], 0, 0, 0);
  }
#pragma unroll
  for (int mt = 0; mt < 4; ++mt)
#pragma unroll
    for (int nt = 0; nt < 4; ++nt)
#pragma unroll
      for (int r = 0; r < 4; ++r) {
        int row = r0 + qr + mt * 16 + lk * 4 + r;
        int col = c0 + qc + nt * 16 + ln;
        C[(long)row * N + col] = acc[mt][nt][r] + bias[col];
      }
}

// ---- persistent cooperative recurrence kernel -----------------------------
// grid 192: [0,64)=L0, [64,128)=MX1, [128,192)=L1; each owns 16 h-cols.
// Per-t slots: H0[t+1], H1[t+1] (bf16, 65 slots), MX1[t] (f32, 64 slots).
// Iter s: L0 computes t=s (polls cnt0>=64s), MX1 t=s-1 (polls cnt0),
// L1 t=s-2 (polls cnt1,cnt2). Arrival: vmcnt drain + own-counter +1.
__global__ void __launch_bounds__(256, 1)
k_chain(const u16* __restrict__ rk0t, const u16* __restrict__ k1t,
        const u16* __restrict__ rk1t, const float* __restrict__ MX0,
        const float* __restrict__ b0, const float* __restrict__ b1,
        float* __restrict__ MX1, u16* __restrict__ H0, u16* __restrict__ H1,
        float* __restrict__ h0f, float* __restrict__ h1f,
        u16* __restrict__ seq1, u32* __restrict__ bar) {
  __shared__ float red[2][3][4][64];
  __shared__ u16 hbS[32][16];
  const int blk = blockIdx.x;
  const int type = blk >> 6;          // 0:L0  1:MX1  2:L1
  const int cb = blk & 63;
  const int j0 = cb << 4;             // 16 h-cols per block
  const int tid = threadIdx.x;
  const int w = tid >> 6, l = tid & 63;
  const int ln = l & 15, lk = l >> 4;
  const int rt = w & 1, kh = w >> 1;  // row-tile (16 rows), K-half (512)

  u32* cnt0 = bar;
  u32* cnt1 = bar + 64;
  u32* cnt2 = bar + 128;

  // entry acquire: buffer_inv drops pre-launch L2 lines -> cached reads of
  // per-t data are guaranteed to miss to L3 (fresh) on first touch.
  if (tid == 0)
    (void)__hip_atomic_load(cnt0, __ATOMIC_ACQUIRE, __HIP_MEMORY_SCOPE_AGENT);
  __syncthreads();

  const u16* Wt = (type == 0) ? rk0t : (type == 1) ? k1t : rk1t;
  const u16* wp = Wt + (long)(j0 + ln) * 1024 + kh * 512 + lk * 8;

  for (int s = 0; s < 66; ++s) {
    // ---- dependency poll (producer-group counters only) ----
    if (tid == 0) {
      const u32 tgt = 64u * (u32)s;
      if (type != 2) {
        while (__hip_atomic_load(cnt0, __ATOMIC_RELAXED,
                                 __HIP_MEMORY_SCOPE_AGENT) < tgt)
          __builtin_amdgcn_s_sleep(1);
      } else {
        while (__hip_atomic_load(cnt1, __ATOMIC_RELAXED,
                                 __HIP_MEMORY_SCOPE_AGENT) < tgt)
          __builtin_amdgcn_s_sleep(1);
        while (__hip_atomic_load(cnt2, __ATOMIC_RELAXED,
                                 __HIP_MEMORY_SCOPE_AGENT) < tgt)
          __builtin_amdgcn_s_sleep(1);
      }
    }
    __syncthreads();

    const int tt = (type == 0) ? s : (type == 1) ? s - 1 : s - 2;
    const bool active = (tt >= 0) && (tt < 64);
    f32x4 acc[3] = {};
    if (active) {
      // h source slot (single-writer, cached read):
      //  L0: h0(tt-1) = H0 slot tt = s;  MX1: h0(tt) = slot tt+1 = s;
      //  L1: h1(tt-1) = H1 slot tt.
      const u16* Ab = (type == 2) ? H1 + (long)tt * 32768
                                  : H0 + (long)s * 32768;
      const u16* hp = Ab + (rt * 16 + ln) * 1024 + kh * 512 + lk * 8;
      bf16x8 afr[16];
#pragma unroll
      for (int ks = 0; ks < 16; ++ks)
        afr[ks] = *(const bf16x8*)(hp + ks * 32);
#pragma unroll
      for (int ks = 0; ks < 16; ++ks) {
        bf16x8 bv0 = *(const bf16x8*)(wp + ks * 32);
        bf16x8 bv1 = *(const bf16x8*)(wp + (1L << 20) + ks * 32);
        bf16x8 bv2 = *(const bf16x8*)(wp + (2L << 20) + ks * 32);
        acc[0] = __builtin_amdgcn_mfma_f32_16x16x32_bf16(afr[ks], bv0, acc[0], 0, 0, 0);
        acc[1] = __builtin_amdgcn_mfma_f32_16x16x32_bf16(afr[ks], bv1, acc[1], 0, 0, 0);
        acc[2] = __builtin_amdgcn_mfma_f32_16x16x32_bf16(afr[ks], bv2, acc[2], 0, 0, 0);
      }
      if (kh == 1) {
#pragma unroll
        for (int g = 0; g < 3; ++g)
#pragma unroll
          for (int r = 0; r < 4; ++r)
            red[rt][g][r][l] = acc[g][r];
      }
    }
    __syncthreads();
    if (active && kh == 0) {
#pragma unroll
      for (int r = 0; r < 4; ++r) {
        const int row = rt * 16 + lk * 4 + r;    // batch b
        const int j = j0 + ln;
        float mz = acc[0][r] + red[rt][0][r][l];
        float mr = acc[1][r] + red[rt][1][r][l];
        float mh = acc[2][r] + red[rt][2][r][l];
        if (type == 1) {
          float* o = MX1 + (long)tt * 98304 + (long)row * 3072;
          astoref(o + j,        mz + b1[j]);
          astoref(o + 1024 + j, mr + b1[1024 + j]);
          astoref(o + 2048 + j, mh + b1[2048 + j]);
        } else {
          const float* bias = (type == 0) ? b0 + 3072 : b1 + 3072;  // b[1]
          float mxz, mxr, mxh;
          if (type == 0) {
            const float* mx = MX0 + ((long)row * 64 + tt) * 3072;
            mxz = mx[j]; mxr = mx[1024 + j]; mxh = mx[2048 + j];
          } else {
            const float* mx = MX1 + (long)tt * 98304 + (long)row * 3072;
            mxz = mx[j]; mxr = mx[1024 + j]; mxh = mx[2048 + j];  // cached
          }
          float miz = mz + bias[j];
          float mir = mr + bias[1024 + j];
          float mih = mh + bias[2048 + j];
          float z  = 1.f / (1.f + expf(-(mxz + miz)));
          float rg = 1.f / (1.f + expf(-(mxr + mir)));
          float hh = tanhf(mxh + rg * mih);
          float* hf = (type == 0) ? h0f : h1f;
          float hold = hf[(long)((tt + 1) & 1) * 32768 + row * 1024 + j];
          float hn = z * hold + (1.f - z) * hh;
          hf[(long)(tt & 1) * 32768 + row * 1024 + j] = hn;    // block-private
          hbS[row][ln] = f2bf(hn);                             // stage bf16
        }
      }
    }
    if (type != 1) {
      __syncthreads();
      if (active) {
        // cooperative u32 writeout of staged 32x16 bf16 tile -> slot tt+1
        const int row = tid >> 3, cp = tid & 7;
        const u32 v = ((const u32*)&hbS[row][0])[cp];
        const int j = j0 + cp * 2;
        if (type == 0) {
          astore32(&H0[(long)(tt + 1) * 32768 + row * 1024 + j], v);
        } else {
          astore32(&H1[(long)(tt + 1) * 32768 + row * 1024 + j], v);
          *(u32*)&seq1[((long)row * 64 + tt) * 1024 + j] = v;  // normal store
        }
      }
    }
    // ---- arrival: own-group counter, after all stores visible at L3 ----
    asm volatile("s_waitcnt vmcnt(0)" ::: "memory");
    __syncthreads();
    if (tid == 0) {
      u32* c = (type == 0) ? cnt0 : (type == 1) ? cnt1 : cnt2;
      __hip_atomic_fetch_add(c, 1u, __ATOMIC_RELAXED,
                             __HIP_MEMORY_SCOPE_AGENT);
    }
  }
}

__global__ void k_states(const float* __restrict__ h0, const float* __restrict__ h1,
                         float* __restrict__ out) {
  int i = blockIdx.x * 256 + threadIdx.x;        // grid 128
  out[i] = h0[i];
  out[32768 + i] = h1[i];
}

extern "C" void kernel_launch(void* const* d_in, const int* in_sizes, int n_in,
                              void* d_out, int out_size, void* d_ws, size_t ws_size,
                              hipStream_t stream) {
  const int*   X     = (const int*)  d_in[0];
  const float* state = (const float*)d_in[1];
  const float* emb   = (const float*)d_in[2];
  const float* k0    = (const float*)d_in[3];
  const float* rk0   = (const float*)d_in[4];
  const float* b0    = (const float*)d_in[5];
  const float* k1    = (const float*)d_in[6];
  const float* rk1   = (const float*)d_in[7];
  const float* b1    = (const float*)d_in[8];
  const float* Wd    = (const float*)d_in[9];
  const float* bd    = (const float*)d_in[10];
  float* out = (float*)d_out;

  char* p = (char*)d_ws;
  size_t off = 0;
  auto alloc = [&](size_t bytes) {
    char* r = p + off;
    off += (bytes + 255) & ~(size_t)255;
    return r;
  };
  u16* k0t  = (u16*)alloc(3072UL * 1536 * 2);
  u16* rk0t = (u16*)alloc(3072UL * 1024 * 2);
  u16* k1t  = (u16*)alloc(3072UL * 1024 * 2);
  u16* rk1t = (u16*)alloc(3072UL * 1024 * 2);
  u16* Wdt  = (u16*)alloc(32000UL * 1024 * 2);
  u16* xin  = (u16*)alloc(2048UL * 1536 * 2);
  float* MX0 = (float*)alloc(2048UL * 3072 * 4);
  float* MX1 = (float*)alloc(64UL * 98304 * 4);    // per-t, 64 slots
  u16* H0   = (u16*)alloc(65UL * 32768 * 2);       // per-t, slots 0..64
  u16* H1   = (u16*)alloc(65UL * 32768 * 2);
  float* h0f = (float*)alloc(2UL * 32768 * 4);
  float* h1f = (float*)alloc(2UL * 32768 * 4);
  u16* seq1 = (u16*)alloc(2048UL * 1024 * 2);
  u32* bar  = (u32*)alloc(BAR_WORDS * 4);
  if (off > ws_size) return;   // ws too small -> poison output signature

  dim3 tb(32, 8);
  k_tconv<<<dim3(3072 / 32, 1536 / 32), tb, 0, stream>>>(k0, k0t, 1536, 3072);
  k_tconv<<<dim3(3072 / 32, 1024 / 32), tb, 0, stream>>>(rk0, rk0t, 1024, 3072);
  k_tconv<<<dim3(3072 / 32, 1024 / 32), tb, 0, stream>>>(k1, k1t, 1024, 3072);
  k_tconv<<<dim3(3072 / 32, 1024 / 32), tb, 0, stream>>>(rk1, rk1t, 1024, 3072);
  k_tconv<<<dim3(32000 / 32, 1024 / 32), tb, 0, stream>>>(Wd, Wdt, 1024, 32000);
  k_embed<<<2048, 256, 0, stream>>>(X, state, emb, xin);
  k_init<<<128, 256, 0, stream>>>(state, H0, H1, h0f, h1f, bar);

  // phase 1: MX0 = xin @ k0t + b0[0]   (grid: rows x cols = 16 x 24)
  k_gemm<<<dim3(16, 24), 256, 0, stream>>>(xin, k0t, b0, MX0, 2048, 3072, 1536);

  // phase 2: recurrence, decoupled per-type sync
  {
    void* args[] = {(void*)&rk0t, (void*)&k1t, (void*)&rk1t, (void*)&MX0,
                    (void*)&b0,   (void*)&b1,  (void*)&MX1,  (void*)&H0,
                    (void*)&H1,   (void*)&h0f, (void*)&h1f,  (void*)&seq1,
                    (void*)&bar};
    hipLaunchCooperativeKernel((void*)k_chain, dim3(CHAIN_BLOCKS), dim3(256),
                               args, 0, stream);
  }

  // phase 3: logits = seq1 @ Wdt + bd  (grid: rows x cols = 16 x 250)
  k_gemm<<<dim3(16, 250), 256, 0, stream>>>(seq1, Wdt, bd, out,
                                            2048, 32000, 1024);
  // phase 4: final states (t=63 -> parity 1)
  k_states<<<128, 256, 0, stream>>>(h0f + 32768, h1f + 32768, out + 65536000UL);
}

// Round 10
// 1152.065 us; speedup vs baseline: 1.7135x; 1.1788x over previous
//
#include <hip/hip_runtime.h>

// Seq2SeqDecoder: 2-layer GRU (reset_after) + logit projection, MI355X/gfx950.
// B=32 T=64 V=32000 E=512 H=1024.
//   phase 0: transpose-convert weights to bf16 [N][K]; build xin bf16; init states
//   phase 1: MX0 = xin @ k0t + b0[0]                  (bf16 MFMA GEMM, 19.3 GF)
//   phase 2: ONE cooperative persistent kernel runs the whole recurrence.
//     R3 22.6us/step -> R9 15.5us/step. Unified model fitting all rounds:
//     same-line atomic RMW arrival under poll pressure ~100-150ns/RMW.
//     R10: NO RMWs. Arrival = sc1 store to per-block flag (64B-spaced, zero
//     serialization). Detect = one wave loads all 64 producer flags in one
//     coalesced load + __all(). MX0 gate values prefetched BEFORE the poll
//     (static data); L1's MX1 values loaded right after poll, before MFMAs.
//     Data path identical to R9 (per-t single-writer buffers, cached reads,
//     sc1 write-through stores).
//   phase 3: logits = seq1 @ Wdt + bd                 (134.2 GF) -> d_out
//   phase 4: final states -> d_out tail

typedef __attribute__((ext_vector_type(8))) short bf16x8;
typedef __attribute__((ext_vector_type(4))) float f32x4;
typedef unsigned short u16;
typedef unsigned int u32;

#define CHAIN_BLOCKS 192
#define BAR_WORDS 3072           // 3 groups x 64 flags x 16-u32 (64B) spacing

__device__ __forceinline__ u16 f2bf(float f) {
  unsigned int x = __float_as_uint(f);
  x += 0x7fffu + ((x >> 16) & 1u);   // RNE
  return (u16)(x >> 16);
}

// sc1 write-through stores (visible at L3 after vmcnt drain)
__device__ __forceinline__ void astoref(float* p, float v) {
  __hip_atomic_store((u32*)p, __float_as_uint(v), __ATOMIC_RELAXED,
                     __HIP_MEMORY_SCOPE_AGENT);
}
__device__ __forceinline__ void astore32(u16* p, u32 v) {
  __hip_atomic_store((u32*)p, v, __ATOMIC_RELAXED, __HIP_MEMORY_SCOPE_AGENT);
}

// ---- transpose + convert: in f32 [R][C] -> out bf16 [C][R] ----------------
__global__ void k_tconv(const float* __restrict__ in, u16* __restrict__ out,
                        int R, int C) {
  __shared__ float t[32][33];
  int tx = threadIdx.x, ty = threadIdx.y;          // 32 x 8
  int c0 = blockIdx.x * 32, r0 = blockIdx.y * 32;
#pragma unroll
  for (int i = 0; i < 4; ++i)
    t[ty + i * 8][tx] = in[(long)(r0 + ty + i * 8) * C + c0 + tx];
  __syncthreads();
#pragma unroll
  for (int i = 0; i < 4; ++i)
    out[(long)(c0 + ty + i * 8) * R + r0 + tx] = f2bf(t[tx][ty + i * 8]);
}

// ---- xin[bt][0:512]=emb[X[bt]], [512:1536]=state[1][b]  (bf16) ------------
__global__ void k_embed(const int* __restrict__ X, const float* __restrict__ state,
                        const float* __restrict__ emb, u16* __restrict__ xin) {
  int bt = blockIdx.x;
  int b = bt >> 6;
  int tok = X[bt];
  const float* er = emb + (long)tok * 512;
  const float* cr = state + 32 * 1024 + b * 1024;  // state[-1] == state[1]
  for (int c = threadIdx.x; c < 1536; c += 256) {
    float v = (c < 512) ? er[c] : cr[c - 512];
    xin[(long)bt * 1536 + c] = f2bf(v);
  }
}

// ---- init: H0/H1 slot0 = bf16(state); h0f/h1f parity1 = state -------------
__global__ void k_init(const float* __restrict__ state, u16* __restrict__ H0,
                       u16* __restrict__ H1, float* __restrict__ h0f,
                       float* __restrict__ h1f, u32* __restrict__ bar) {
  int i = blockIdx.x * 256 + threadIdx.x;          // grid 128 -> 32768
  if (i < BAR_WORDS) bar[i] = 0u;                  // flags reset
  float v0 = state[i], v1 = state[32768 + i];
  H0[i] = f2bf(v0);             // slot 0 = h0(-1)
  h0f[32768 + i] = v0;          // parity 1
  H1[i] = f2bf(v1);             // slot 0 = h1(-1)
  h1f[32768 + i] = v1;
}

// ---- bf16 GEMM: C[M,N]f32 = A[M,K] @ Bt[N,K]^T + bias[N] ------------------
__global__ void k_gemm(const u16* __restrict__ A, const u16* __restrict__ Bt,
                       const float* __restrict__ bias, float* __restrict__ C,
                       int M, int N, int K) {
  __shared__ u16 As[128][40];
  __shared__ u16 Bs[128][40];
  int tid = threadIdx.x;
  int w = tid >> 6, l = tid & 63;
  int ln = l & 15, lk = l >> 4;
  int r0 = blockIdx.x * 128, c0 = blockIdx.y * 128;
  int qr = (w & 1) * 64, qc = (w >> 1) * 64;
  int sr = tid >> 1, sc = (tid & 1) * 16;
  const u16* Ap = A + (long)(r0 + sr) * K + sc;
  const u16* Bp = Bt + (long)(c0 + sr) * K + sc;
  f32x4 acc[4][4] = {};
  for (int kt = 0; kt < K; kt += 32) {
    bf16x8 a0 = *(const bf16x8*)(Ap + kt);
    bf16x8 a1 = *(const bf16x8*)(Ap + kt + 8);
    bf16x8 b0 = *(const bf16x8*)(Bp + kt);
    bf16x8 b1 = *(const bf16x8*)(Bp + kt + 8);
    __syncthreads();
    *(bf16x8*)(&As[sr][sc]) = a0;  *(bf16x8*)(&As[sr][sc + 8]) = a1;
    *(bf16x8*)(&Bs[sr][sc]) = b0;  *(bf16x8*)(&Bs[sr][sc + 8]) = b1;
    __syncthreads();
    bf16x8 af[4], bfv[4];
#pragma unroll
    for (int mt = 0; mt < 4; ++mt)
      af[mt] = *(const bf16x8*)(&As[qr + mt * 16 + ln][lk * 8]);
#pragma unroll
    for (int nt = 0; nt < 4; ++nt)
      bfv[nt] = *(const bf16x8*)(&Bs[qc + nt * 16 + ln][lk * 8]);
#pragma unroll
    for (int mt = 0; mt < 4; ++mt)
#pragma unroll
      for (int nt = 0; nt < 4; ++nt)
        acc[mt][nt] = __builtin_amdgcn_mfma_f32_16x16x32_bf16(
            af[mt], bfv[nt], acc[mt][nt], 0, 0, 0);
  }
#pragma unroll
  for (int mt = 0; mt < 4; ++mt)
#pragma unroll
    for (int nt = 0; nt < 4; ++nt)
#pragma unroll
      for (int r = 0; r < 4; ++r) {
        int row = r0 + qr + mt * 16 + lk * 4 + r;
        int col = c0 + qc + nt * 16 + ln;
        C[(long)row * N + col] = acc[mt][nt][r] + bias[col];
      }
}

// ---- persistent cooperative recurrence kernel -----------------------------
// grid 192: [0,64)=L0, [64,128)=MX1, [128,192)=L1; each owns 16 h-cols.
// Per-t slots: H0[t+1], H1[t+1] (65 slots), MX1[t] (64 slots).
// Flags: FL[type][cb] at bar[type*1024 + cb*16], set to s+1 at end of iter s.
// Iter s dependencies (uniform): L0/MX1 need FL0[*]>=s; L1 needs FL1,FL2[*]>=s.
__global__ void __launch_bounds__(256, 1)
k_chain(const u16* __restrict__ rk0t, const u16* __restrict__ k1t,
        const u16* __restrict__ rk1t, const float* __restrict__ MX0,
        const float* __restrict__ b0, const float* __restrict__ b1,
        float* __restrict__ MX1, u16* __restrict__ H0, u16* __restrict__ H1,
        float* __restrict__ h0f, float* __restrict__ h1f,
        u16* __restrict__ seq1, u32* __restrict__ bar) {
  __shared__ float red[2][3][4][64];
  __shared__ u16 hbS[32][16];
  const int blk = blockIdx.x;
  const int type = blk >> 6;          // 0:L0  1:MX1  2:L1
  const int cb = blk & 63;
  const int j0 = cb << 4;             // 16 h-cols per block
  const int tid = threadIdx.x;
  const int w = tid >> 6, l = tid & 63;
  const int ln = l & 15, lk = l >> 4;
  const int rt = w & 1, kh = w >> 1;  // row-tile (16 rows), K-half (512)

  // entry acquire: buffer_inv drops pre-launch L2 lines (per-t buffers fresh)
  if (tid == 0)
    (void)__hip_atomic_load(bar, __ATOMIC_ACQUIRE, __HIP_MEMORY_SCOPE_AGENT);
  __syncthreads();

  const u16* Wt = (type == 0) ? rk0t : (type == 1) ? k1t : rk1t;
  const u16* wp = Wt + (long)(j0 + ln) * 1024 + kh * 512 + lk * 8;
  u32* myflag = bar + type * 1024 + cb * 16;

  for (int s = 0; s < 66; ++s) {
    const int tt = (type == 0) ? s : (type == 1) ? s - 1 : s - 2;
    const bool active = (tt >= 0) && (tt < 64);

    // ---- MX0 prefetch (static data, issued BEFORE the poll) ----
    float pf[4][3];
    if (type == 0 && kh == 0 && active) {
      const int j = j0 + ln;
#pragma unroll
      for (int r = 0; r < 4; ++r) {
        const float* mx = MX0 + (((long)(rt * 16 + lk * 4 + r)) * 64 + tt) * 3072;
        pf[r][0] = mx[j]; pf[r][1] = mx[1024 + j]; pf[r][2] = mx[2048 + j];
      }
    }

    // ---- dependency poll: wave-parallel flag scan, no RMWs ----
    if (tid < 64) {
      const u32 tgt = (u32)s;
      if (type != 2) {
        const u32* f = bar + tid * 16;                       // FL0
        while (true) {
          u32 v = __hip_atomic_load(f, __ATOMIC_RELAXED,
                                    __HIP_MEMORY_SCOPE_AGENT);
          if (__all(v >= tgt)) break;
          __builtin_amdgcn_s_sleep(1);
        }
      } else {
        const u32* fa = bar + 1024 + tid * 16;               // FL1
        const u32* fb = bar + 2048 + tid * 16;               // FL2
        while (true) {
          u32 va = __hip_atomic_load(fa, __ATOMIC_RELAXED,
                                     __HIP_MEMORY_SCOPE_AGENT);
          u32 vb = __hip_atomic_load(fb, __ATOMIC_RELAXED,
                                     __HIP_MEMORY_SCOPE_AGENT);
          if (__all(va >= tgt && vb >= tgt)) break;
          __builtin_amdgcn_s_sleep(1);
        }
      }
    }
    __syncthreads();

    f32x4 acc[3] = {};
    if (active) {
      // L1's MX1 gate values: load right after poll, before MFMAs (L3 latency
      // hides under the matmul)
      if (type == 2 && kh == 0) {
        const int j = j0 + ln;
#pragma unroll
        for (int r = 0; r < 4; ++r) {
          const float* mx = MX1 + (long)tt * 98304 +
                            (long)(rt * 16 + lk * 4 + r) * 3072;
          pf[r][0] = mx[j]; pf[r][1] = mx[1024 + j]; pf[r][2] = mx[2048 + j];
        }
      }
      // h source slot (single-writer, cached read)
      const u16* Ab = (type == 2) ? H1 + (long)tt * 32768
                                  : H0 + (long)s * 32768;
      const u16* hp = Ab + (rt * 16 + ln) * 1024 + kh * 512 + lk * 8;
      bf16x8 afr[16];
#pragma unroll
      for (int ks = 0; ks < 16; ++ks)
        afr[ks] = *(const bf16x8*)(hp + ks * 32);
#pragma unroll
      for (int ks = 0; ks < 16; ++ks) {
        bf16x8 bv0 = *(const bf16x8*)(wp + ks * 32);
        bf16x8 bv1 = *(const bf16x8*)(wp + (1L << 20) + ks * 32);
        bf16x8 bv2 = *(const bf16x8*)(wp + (2L << 20) + ks * 32);
        acc[0] = __builtin_amdgcn_mfma_f32_16x16x32_bf16(afr[ks], bv0, acc[0], 0, 0, 0);
        acc[1] = __builtin_amdgcn_mfma_f32_16x16x32_bf16(afr[ks], bv1, acc[1], 0, 0, 0);
        acc[2] = __builtin_amdgcn_mfma_f32_16x16x32_bf16(afr[ks], bv2, acc[2], 0, 0, 0);
      }
      if (kh == 1) {
#pragma unroll
        for (int g = 0; g < 3; ++g)
#pragma unroll
          for (int r = 0; r < 4; ++r)
            red[rt][g][r][l] = acc[g][r];
      }
    }
    __syncthreads();
    if (active && kh == 0) {
#pragma unroll
      for (int r = 0; r < 4; ++r) {
        const int row = rt * 16 + lk * 4 + r;    // batch b
        const int j = j0 + ln;
        float mz = acc[0][r] + red[rt][0][r][l];
        float mr = acc[1][r] + red[rt][1][r][l];
        float mh = acc[2][r] + red[rt][2][r][l];
        if (type == 1) {
          float* o = MX1 + (long)tt * 98304 + (long)row * 3072;
          astoref(o + j,        mz + b1[j]);
          astoref(o + 1024 + j, mr + b1[1024 + j]);
          astoref(o + 2048 + j, mh + b1[2048 + j]);
        } else {
          const float* bias = (type == 0) ? b0 + 3072 : b1 + 3072;  // b[1]
          float miz = mz + bias[j];
          float mir = mr + bias[1024 + j];
          float mih = mh + bias[2048 + j];
          float z  = 1.f / (1.f + expf(-(pf[r][0] + miz)));
          float rg = 1.f / (1.f + expf(-(pf[r][1] + mir)));
          float hh = tanhf(pf[r][2] + rg * mih);
          float* hf = (type == 0) ? h0f : h1f;
          float hold = hf[(long)((tt + 1) & 1) * 32768 + row * 1024 + j];
          float hn = z * hold + (1.f - z) * hh;
          hf[(long)(tt & 1) * 32768 + row * 1024 + j] = hn;    // block-private
          hbS[row][ln] = f2bf(hn);                             // stage bf16
        }
      }
    }
    if (type != 1) {
      __syncthreads();
      if (active) {
        // cooperative u32 writeout of staged 32x16 bf16 tile -> slot tt+1
        const int row = tid >> 3, cp = tid & 7;
        const u32 v = ((const u32*)&hbS[row][0])[cp];
        const int j = j0 + cp * 2;
        if (type == 0) {
          astore32(&H0[(long)(tt + 1) * 32768 + row * 1024 + j], v);
        } else {
          astore32(&H1[(long)(tt + 1) * 32768 + row * 1024 + j], v);
          *(u32*)&seq1[((long)row * 64 + tt) * 1024 + j] = v;  // normal store
        }
      }
    }
    // ---- arrival: drain stores, then ONE sc1 flag store (no RMW) ----
    asm volatile("s_waitcnt vmcnt(0)" ::: "memory");
    __syncthreads();
    if (tid == 0)
      __hip_atomic_store(myflag, (u32)(s + 1), __ATOMIC_RELAXED,
                         __HIP_MEMORY_SCOPE_AGENT);
  }
}

__global__ void k_states(const float* __restrict__ h0, const float* __restrict__ h1,
                         float* __restrict__ out) {
  int i = blockIdx.x * 256 + threadIdx.x;        // grid 128
  out[i] = h0[i];
  out[32768 + i] = h1[i];
}

extern "C" void kernel_launch(void* const* d_in, const int* in_sizes, int n_in,
                              void* d_out, int out_size, void* d_ws, size_t ws_size,
                              hipStream_t stream) {
  const int*   X     = (const int*)  d_in[0];
  const float* state = (const float*)d_in[1];
  const float* emb   = (const float*)d_in[2];
  const float* k0    = (const float*)d_in[3];
  const float* rk0   = (const float*)d_in[4];
  const float* b0    = (const float*)d_in[5];
  const float* k1    = (const float*)d_in[6];
  const float* rk1   = (const float*)d_in[7];
  const float* b1    = (const float*)d_in[8];
  const float* Wd    = (const float*)d_in[9];
  const float* bd    = (const float*)d_in[10];
  float* out = (float*)d_out;

  char* p = (char*)d_ws;
  size_t off = 0;
  auto alloc = [&](size_t bytes) {
    char* r = p + off;
    off += (bytes + 255) & ~(size_t)255;
    return r;
  };
  u16* k0t  = (u16*)alloc(3072UL * 1536 * 2);
  u16* rk0t = (u16*)alloc(3072UL * 1024 * 2);
  u16* k1t  = (u16*)alloc(3072UL * 1024 * 2);
  u16* rk1t = (u16*)alloc(3072UL * 1024 * 2);
  u16* Wdt  = (u16*)alloc(32000UL * 1024 * 2);
  u16* xin  = (u16*)alloc(2048UL * 1536 * 2);
  float* MX0 = (float*)alloc(2048UL * 3072 * 4);
  float* MX1 = (float*)alloc(64UL * 98304 * 4);    // per-t, 64 slots
  u16* H0   = (u16*)alloc(65UL * 32768 * 2);       // per-t, slots 0..64
  u16* H1   = (u16*)alloc(65UL * 32768 * 2);
  float* h0f = (float*)alloc(2UL * 32768 * 4);
  float* h1f = (float*)alloc(2UL * 32768 * 4);
  u16* seq1 = (u16*)alloc(2048UL * 1024 * 2);
  u32* bar  = (u32*)alloc(BAR_WORDS * 4);
  if (off > ws_size) return;   // ws too small -> poison output signature

  dim3 tb(32, 8);
  k_tconv<<<dim3(3072 / 32, 1536 / 32), tb, 0, stream>>>(k0, k0t, 1536, 3072);
  k_tconv<<<dim3(3072 / 32, 1024 / 32), tb, 0, stream>>>(rk0, rk0t, 1024, 3072);
  k_tconv<<<dim3(3072 / 32, 1024 / 32), tb, 0, stream>>>(k1, k1t, 1024, 3072);
  k_tconv<<<dim3(3072 / 32, 1024 / 32), tb, 0, stream>>>(rk1, rk1t, 1024, 3072);
  k_tconv<<<dim3(32000 / 32, 1024 / 32), tb, 0, stream>>>(Wd, Wdt, 1024, 32000);
  k_embed<<<2048, 256, 0, stream>>>(X, state, emb, xin);
  k_init<<<128, 256, 0, stream>>>(state, H0, H1, h0f, h1f, bar);

  // phase 1: MX0 = xin @ k0t + b0[0]   (grid: rows x cols = 16 x 24)
  k_gemm<<<dim3(16, 24), 256, 0, stream>>>(xin, k0t, b0, MX0, 2048, 3072, 1536);

  // phase 2: recurrence, flag-array sync (no RMWs)
  {
    void* args[] = {(void*)&rk0t, (void*)&k1t, (void*)&rk1t, (void*)&MX0,
                    (void*)&b0,   (void*)&b1,  (void*)&MX1,  (void*)&H0,
                    (void*)&H1,   (void*)&h0f, (void*)&h1f,  (void*)&seq1,
                    (void*)&bar};
    hipLaunchCooperativeKernel((void*)k_chain, dim3(CHAIN_BLOCKS), dim3(256),
                               args, 0, stream);
  }

  // phase 3: logits = seq1 @ Wdt + bd  (grid: rows x cols = 16 x 250)
  k_gemm<<<dim3(16, 250), 256, 0, stream>>>(seq1, Wdt, bd, out,
                                            2048, 32000, 1024);
  // phase 4: final states (t=63 -> parity 1)
  k_states<<<128, 256, 0, stream>>>(h0f + 32768, h1f + 32768, out + 65536000UL);
}